// Round 6
// baseline (276.798 us; speedup 1.0000x reference)
//
#include <hip/hip_runtime.h>
#include <hip/hip_bf16.h>
#include <math.h>

#define B_ 4
#define T_ 4096
#define D_ 2048
#define H_ 128
#define M_ (B_*T_)   // 16384 rows

typedef __bf16 bf16;
typedef __attribute__((ext_vector_type(8))) __bf16 bf16x8;
typedef __attribute__((ext_vector_type(4))) float f32x4;
typedef __attribute__((ext_vector_type(16))) float f32x16;

#define MFMA32(a,b,c) __builtin_amdgcn_mfma_f32_32x32x16_bf16(a,b,c,0,0,0)

typedef __attribute__((address_space(3))) unsigned int lds_u32_t;
typedef const __attribute__((address_space(1))) unsigned int glb_u32_t;

__device__ __forceinline__ void cp16(void* lds, const void* g) {
    __builtin_amdgcn_global_load_lds((glb_u32_t*)g, (lds_u32_t*)lds, 16, 0, 0);
}

// ws layout (bytes)
#define QOFF   0u
#define KOFF   (4u<<20)
#define VTOFF  (8u<<20)
#define WTOFF  (12u<<20)          // 3 * 128 * 2048 bf16 = 1.5 MiB
#define OPOFF  (14u<<20)          // ks=1 partial O, fp32, 8 MiB
#define LPOFF  (OPOFF + 8388608u) // l partials [2][16384] fp32

// ---------------------------------------------------------------------------
// W convert+transpose (coalesced): W[2048][128] fp32 -> Wt[mat][128][2048]
// bf16. Wq pre-scaled by log2(e)/sqrt(H) so attention uses bare exp2.
// Grid 96 = 3 mats x 32 k-tiles(64).
// ---------------------------------------------------------------------------
__global__ __launch_bounds__(256) void cvtw_kernel(
    const float* __restrict__ Wq, const float* __restrict__ Wk,
    const float* __restrict__ Wv, bf16* __restrict__ Wtb)
{
    __shared__ __align__(16) bf16 U[128 * 72];   // [n][k], stride 72
    const int tid = threadIdx.x;
    const int m  = blockIdx.x >> 5;              // 0..2
    const int kt = blockIdx.x & 31;              // 0..31
    const int k0 = kt * 64;
    const float* W = (m == 0) ? Wq : ((m == 1) ? Wk : Wv);
    // 1/sqrt(128) * log2(e)
    const float sc = (m == 0) ? 0.12753102105128444f : 1.0f;

    #pragma unroll
    for (int u = 0; u < 8; u++) {
        int id = tid + u * 256;          // 2048 float4
        int kr = id >> 5, c4 = id & 31;
        float4 v = *(const float4*)(W + (size_t)(k0 + kr) * H_ + c4 * 4);
        U[(c4*4 + 0) * 72 + kr] = (bf16)(v.x * sc);
        U[(c4*4 + 1) * 72 + kr] = (bf16)(v.y * sc);
        U[(c4*4 + 2) * 72 + kr] = (bf16)(v.z * sc);
        U[(c4*4 + 3) * 72 + kr] = (bf16)(v.w * sc);
    }
    __syncthreads();
    #pragma unroll
    for (int u = 0; u < 4; u++) {
        int id = tid + u * 256;          // 1024 chunks of 16B
        int n = id >> 3, kc = id & 7;
        bf16x8 v = *(const bf16x8*)((const char*)U + n * 144 + kc * 16);
        *(bf16x8*)((char*)Wtb + (size_t)m * 524288 + (size_t)n * 4096
                   + k0 * 2 + kc * 16) = v;
    }
}

// ---------------------------------------------------------------------------
// Fused QKV projection, 32x32x16 MFMA. Block 512 thr / 8 waves, M-tile 64.
// Wave = 32 rows x 96 flat-N cols (flat N = 3 mats x 128).
// Double-buffered LDS: X (VALU-staged fp32->bf16), W (cp16).
// ---------------------------------------------------------------------------
__global__ __launch_bounds__(512, 2) void proj_kernel(
    const float* __restrict__ X, const bf16* __restrict__ Wtb,
    bf16* __restrict__ Qb, bf16* __restrict__ Kb, bf16* __restrict__ Vtb)
{
    __shared__ __align__(16) char smem[114688];
    // xs bufs at 0 / 8192 ; W bufs at 16384 / 65536 (each 48 KB)

    const int tid = threadIdx.x;
    const int w = tid >> 6, lane = tid & 63;
    const int c31 = lane & 31, kh = lane >> 5;
    const int mh = w >> 2;             // row half (32 rows)
    const int ng = w & 3;              // 96-col group
    const int m0 = blockIdx.x * 64;

    f32x16 acc[3];
    #pragma unroll
    for (int t = 0; t < 3; t++)
        #pragma unroll
        for (int r = 0; r < 16; r++) acc[t][r] = 0.f;

    // prologue: stage k-tile 0 into buf 0
    #pragma unroll
    for (int u = 0; u < 6; u++) {
        int s = tid + u * 512;
        int n = s >> 3, ccs = s & 7;
        int kc = ccs ^ (n & 7);
        int mat = n >> 7, ncol = n & 127;
        cp16(smem + 16384 + s * 16,
             (const char*)Wtb + (size_t)mat * 524288 + (size_t)ncol * 4096 + kc * 16);
    }
    {
        int r = tid >> 3, cc = tid & 7;
        const float* src = X + (size_t)(m0 + r) * D_ + cc * 8;
        float4 v0 = *(const float4*)src;
        float4 v1 = *(const float4*)(src + 4);
        union { bf16 h[8]; uint4 u4; } pk;
        pk.h[0]=(bf16)v0.x; pk.h[1]=(bf16)v0.y; pk.h[2]=(bf16)v0.z; pk.h[3]=(bf16)v0.w;
        pk.h[4]=(bf16)v1.x; pk.h[5]=(bf16)v1.y; pk.h[6]=(bf16)v1.z; pk.h[7]=(bf16)v1.w;
        *(uint4*)(smem + (r * 8 + (cc ^ (r & 7))) * 16) = pk.u4;
    }
    __syncthreads();

    for (int it = 0; it < 32; it++) {
        const int cur = it & 1;
        char* xcur = smem + cur * 8192;
        char* wcur = smem + 16384 + cur * 49152;
        float4 xv0, xv1;
        if (it < 31) {
            const int k1 = (it + 1) * 64;
            char* wnxt = smem + 16384 + (cur ^ 1) * 49152;
            #pragma unroll
            for (int u = 0; u < 6; u++) {
                int s = tid + u * 512;
                int n = s >> 3, ccs = s & 7;
                int kc = ccs ^ (n & 7);
                int mat = n >> 7, ncol = n & 127;
                cp16(wnxt + s * 16,
                     (const char*)Wtb + (size_t)mat * 524288 + (size_t)ncol * 4096
                     + k1 * 2 + kc * 16);
            }
            int r = tid >> 3, cc = tid & 7;
            const float* src = X + (size_t)(m0 + r) * D_ + k1 + cc * 8;
            xv0 = *(const float4*)src;
            xv1 = *(const float4*)(src + 4);
        }
        // compute on cur
        #pragma unroll
        for (int s = 0; s < 4; s++) {
            int c = s * 2 + kh;
            int rr = mh * 32 + c31;
            bf16x8 af = *(const bf16x8*)(xcur + (rr * 8 + (c ^ (rr & 7))) * 16);
            #pragma unroll
            for (int t = 0; t < 3; t++) {
                int n = ng * 96 + t * 32 + c31;
                bf16x8 bfr = *(const bf16x8*)(wcur + (n * 8 + (c ^ (n & 7))) * 16);
                acc[t] = MFMA32(af, bfr, acc[t]);
            }
        }
        if (it < 31) {
            char* xnxt = smem + (cur ^ 1) * 8192;
            int r = tid >> 3, cc = tid & 7;
            union { bf16 h[8]; uint4 u4; } pk;
            pk.h[0]=(bf16)xv0.x; pk.h[1]=(bf16)xv0.y; pk.h[2]=(bf16)xv0.z; pk.h[3]=(bf16)xv0.w;
            pk.h[4]=(bf16)xv1.x; pk.h[5]=(bf16)xv1.y; pk.h[6]=(bf16)xv1.z; pk.h[7]=(bf16)xv1.w;
            *(uint4*)(xnxt + (r * 8 + (cc ^ (r & 7))) * 16) = pk.u4;
        }
        __syncthreads();
    }

    // ---- epilogue ----
    // V^T (flat n >= 256): direct global stores (C regs = 4 consecutive rows)
    #pragma unroll
    for (int t = 0; t < 3; t++) {
        int nb = ng * 96 + t * 32;
        if ((nb >> 7) == 2) {
            int ncol = (nb & 127) + c31;
            #pragma unroll
            for (int g = 0; g < 4; g++) {
                int m = m0 + mh * 32 + g * 8 + kh * 4;
                union { bf16 h[4]; uint2 u2; } pk;
                #pragma unroll
                for (int e = 0; e < 4; e++) pk.h[e] = (bf16)acc[t][g*4 + e];
                *(uint2*)((char*)Vtb + (size_t)ncol * 32768 + (size_t)m * 2) = pk.u2;
            }
        }
    }
    // Q then K: stash to LDS (pitch 136 bf16 = 272 B), cooperative store
    bf16* U = (bf16*)smem;
    #pragma unroll
    for (int mat = 0; mat < 2; mat++) {
        __syncthreads();
        #pragma unroll
        for (int t = 0; t < 3; t++) {
            int nb = ng * 96 + t * 32;
            if ((nb >> 7) == mat) {
                int lcol = (nb & 127) + c31;
                #pragma unroll
                for (int r = 0; r < 16; r++) {
                    int row = mh * 32 + (r & 3) + 8 * (r >> 2) + 4 * kh;
                    U[row * 136 + lcol] = (bf16)acc[t][r];
                }
            }
        }
        __syncthreads();
        bf16* og = (mat == 0) ? Qb : Kb;
        #pragma unroll
        for (int u = 0; u < 2; u++) {
            int id = tid + u * 512;
            int rr = id >> 4, cc = id & 15;
            bf16x8 v = *(const bf16x8*)((const char*)U + rr * 272 + cc * 16);
            *(bf16x8*)((char*)og + (size_t)(m0 + rr) * 256 + cc * 16) = v;
        }
    }
}

// ---------------------------------------------------------------------------
// Flash attention, 32x32x16 MFMA, streaming sum-exp2 (Q pre-scaled by log2e).
// Grid 512. XCD-aware: bx&7 = (b*2+ks) slice, so under round-robin dispatch
// each XCD hosts one slice's 64 q-tile blocks -> K/V slice L2-resident.
// Block 256 thr / 4 waves, Q-tile 64. Double-buffered K/V staging.
// ---------------------------------------------------------------------------
__global__ __launch_bounds__(256, 2) void attn_kernel(
    const bf16* __restrict__ Qb, const bf16* __restrict__ Kb,
    const bf16* __restrict__ Vtb,
    float* __restrict__ Out0, float* __restrict__ Opart1,
    float* __restrict__ lpart)
{
    __shared__ __align__(16) char smem[75264];
    // Ks bufs: 0 / 16384 ; Vs bufs: 32768 / 49152 ; Ps: 65536 (64x144B) ;
    // lred: 74752 (2*64 f32)

    const int tid = threadIdx.x;
    const int w = tid >> 6, lane = tid & 63;
    const int c31 = lane & 31, kh = lane >> 5;

    const int bx = blockIdx.x;
    const int slice = bx & 7;      // -> XCD id under round-robin dispatch
    const int qt = bx >> 3;
    const int b  = slice >> 1;
    const int ks = slice & 1;
    const int row0 = b*T_ + qt*64;
    const int kvrow = b*T_ + ks*2048;

    const int mh  = w >> 1;        // q-row half (S and PV)
    const int kh2 = w & 1;         // key half (S)
    const int nq0 = (w & 1) * 2;   // n-quarter base (PV)

    // Q fragments: A-operand, rows mh*32+c31, k = s*16 + kh*8 + j
    bf16x8 qf[8];
    {
        const char* qrow = (const char*)Qb + (size_t)(row0 + mh*32 + c31)*256 + kh*16;
        #pragma unroll
        for (int s = 0; s < 8; s++)
            qf[s] = *(const bf16x8*)(qrow + s*32);
    }

    f32x16 o0, o1;
    #pragma unroll
    for (int r = 0; r < 16; r++) { o0[r] = 0.f; o1[r] = 0.f; }
    float lsum[16];
    #pragma unroll
    for (int r = 0; r < 16; r++) lsum[r] = 0.f;

    // prologue: stage tile 0 into buf 0
    #pragma unroll
    for (int u = 0; u < 4; u++) {
        int s = tid + u*256;
        int r = s >> 4, csw = s & 15;
        int cg = (csw & 8) | ((csw ^ r) & 7);
        cp16(smem + s*16, (const char*)Kb + (size_t)(kvrow + r)*256 + cg*16);
    }
    #pragma unroll
    for (int u = 0; u < 4; u++) {
        int s = tid + u*256;
        int h = s >> 3, ccsw = s & 7;
        int cc = (ccsw ^ h) & 7;
        cp16(smem + 32768 + s*16,
             (const char*)Vtb + (size_t)h*32768 + (size_t)kvrow*2 + cc*16);
    }
    __syncthreads();

    for (int it = 0; it < 32; it++) {
        const int cur = it & 1;
        char* ksb = smem + cur*16384;
        char* vsb = smem + 32768 + cur*16384;
        if (it < 31) {
            const int knx = kvrow + (it + 1)*64;
            char* kn = smem + (cur ^ 1)*16384;
            char* vn = smem + 32768 + (cur ^ 1)*16384;
            #pragma unroll
            for (int u = 0; u < 4; u++) {
                int s = tid + u*256;
                int r = s >> 4, csw = s & 15;
                int cg = (csw & 8) | ((csw ^ r) & 7);
                cp16(kn + s*16, (const char*)Kb + (size_t)(knx + r)*256 + cg*16);
            }
            #pragma unroll
            for (int u = 0; u < 4; u++) {
                int s = tid + u*256;
                int h = s >> 3, ccsw = s & 7;
                int cc = (ccsw ^ h) & 7;
                cp16(vn + s*16,
                     (const char*)Vtb + (size_t)h*32768 + (size_t)knx*2 + cc*16);
            }
        }

        // S = Q K^T : one 32x32 tile per wave (rows mh*32.., keys kh2*32..)
        f32x16 sacc;
        #pragma unroll
        for (int r = 0; r < 16; r++) sacc[r] = 0.f;
        const int key = kh2*32 + c31;
        #pragma unroll
        for (int s = 0; s < 8; s++) {
            int ck = s*2 + kh;
            int slot = key*16 + ((ck & 8) | ((ck ^ key) & 7));
            bf16x8 kf = *(const bf16x8*)(ksb + slot*16);
            sacc = MFMA32(qf[s], kf, sacc);
        }
        // exp2 -> P[m][key] (pitch 72 bf16 = 144 B)
        bf16* Pp = (bf16*)(smem + 65536);
        #pragma unroll
        for (int r = 0; r < 16; r++) {
            float p = exp2f(sacc[r]);
            lsum[r] += p;
            int irow = (r & 3) + 8*(r >> 2) + 4*kh;
            Pp[(mh*32 + irow)*72 + key] = (bf16)p;
        }
        __syncthreads();

        // O += P V : A=P (rows mh*32+c31), B=V^T (cols nq0*32.. / +32)
        #pragma unroll
        for (int s2 = 0; s2 < 4; s2++) {
            bf16x8 pf = *(const bf16x8*)(smem + 65536
                           + (mh*32 + c31)*144 + s2*32 + kh*16);
            int cv = s2*2 + kh;
            int n0 = nq0*32 + c31;
            int n1 = n0 + 32;
            bf16x8 vf0 = *(const bf16x8*)(vsb + (n0*8 + ((cv ^ n0) & 7))*16);
            bf16x8 vf1 = *(const bf16x8*)(vsb + (n1*8 + ((cv ^ n1) & 7))*16);
            o0 = MFMA32(pf, vf0, o0);
            o1 = MFMA32(pf, vf1, o1);
        }
        __syncthreads();
    }

    // l reduction: sum over c31 lanes, combine key halves via LDS
    #pragma unroll
    for (int r = 0; r < 16; r++) {
        float v = lsum[r];
        v += __shfl_xor(v, 1); v += __shfl_xor(v, 2); v += __shfl_xor(v, 4);
        v += __shfl_xor(v, 8); v += __shfl_xor(v, 16);
        if (c31 == 0) {
            int irow = (r & 3) + 8*(r >> 2) + 4*kh;
            ((float*)(smem + 74752))[kh2*64 + mh*32 + irow] = v;
        }
    }
    __syncthreads();
    if (tid < 64) {
        const float* lr = (const float*)(smem + 74752);
        lpart[ks*M_ + row0 + tid] = lr[tid] + lr[64 + tid];
    }
    float* Od = (ks == 0) ? Out0 : Opart1;
    #pragma unroll
    for (int r = 0; r < 16; r++) {
        int m = mh*32 + (r & 3) + 8*(r >> 2) + 4*kh;
        Od[(size_t)(row0 + m)*H_ + nq0*32 + c31] = o0[r];
        Od[(size_t)(row0 + m)*H_ + nq0*32 + 32 + c31] = o1[r];
    }
}

// ---------------------------------------------------------------------------
// Merge: out = (Oa + Ob) / (la + lb)
// ---------------------------------------------------------------------------
__global__ __launch_bounds__(256) void merge_kernel(
    float* __restrict__ Out, const float* __restrict__ Op1,
    const float* __restrict__ lp)
{
    int id = blockIdx.x * 256 + threadIdx.x;
    int row = id >> 5;
    float inv = 1.0f / (lp[row] + lp[M_ + row]);
    float4 a = *(const float4*)(Out + (size_t)id*4);
    float4 bq = *(const float4*)(Op1 + (size_t)id*4);
    float4 rr;
    rr.x = (a.x + bq.x) * inv; rr.y = (a.y + bq.y) * inv;
    rr.z = (a.z + bq.z) * inv; rr.w = (a.w + bq.w) * inv;
    *(float4*)(Out + (size_t)id*4) = rr;
}

extern "C" void kernel_launch(void* const* d_in, const int* in_sizes, int n_in,
                              void* d_out, int out_size, void* d_ws, size_t ws_size,
                              hipStream_t stream) {
    const float* x  = (const float*)d_in[0];
    const float* Wq = (const float*)d_in[1];
    const float* Wk = (const float*)d_in[2];
    const float* Wv = (const float*)d_in[3];
    float* outp = (float*)d_out;
    char* ws = (char*)d_ws;

    bf16* Qb  = (bf16*)(ws + QOFF);
    bf16* Kb  = (bf16*)(ws + KOFF);
    bf16* Vtb = (bf16*)(ws + VTOFF);
    bf16* Wtb = (bf16*)(ws + WTOFF);
    float* Op1 = (float*)(ws + OPOFF);
    float* lp  = (float*)(ws + LPOFF);

    cvtw_kernel<<<96, 256, 0, stream>>>(Wq, Wk, Wv, Wtb);
    proj_kernel<<<M_/64, 512, 0, stream>>>(x, Wtb, Qb, Kb, Vtb);
    attn_kernel<<<512, 256, 0, stream>>>(Qb, Kb, Vtb, outp, Op1, lp);
    merge_kernel<<<2048, 256, 0, stream>>>(outp, Op1, lp);
}

// Round 7
// 266.805 us; speedup vs baseline: 1.0375x; 1.0375x over previous
//
#include <hip/hip_runtime.h>
#include <hip/hip_bf16.h>
#include <math.h>

#define B_ 4
#define T_ 4096
#define D_ 2048
#define H_ 128
#define M_ (B_*T_)   // 16384 rows

typedef __bf16 bf16;
typedef __attribute__((ext_vector_type(8))) __bf16 bf16x8;
typedef __attribute__((ext_vector_type(4))) float f32x4;
typedef __attribute__((ext_vector_type(16))) float f32x16;

#define MFMA16(a,b,c) __builtin_amdgcn_mfma_f32_16x16x32_bf16(a,b,c,0,0,0)
#define MFMA32(a,b,c) __builtin_amdgcn_mfma_f32_32x32x16_bf16(a,b,c,0,0,0)

typedef __attribute__((address_space(3))) unsigned int lds_u32_t;
typedef const __attribute__((address_space(1))) unsigned int glb_u32_t;

__device__ __forceinline__ void cp16(void* lds, const void* g) {
    __builtin_amdgcn_global_load_lds((glb_u32_t*)g, (lds_u32_t*)lds, 16, 0, 0);
}

// ws layout (bytes)
#define QOFF   0u
#define KOFF   (4u<<20)
#define VTOFF  (8u<<20)
#define WTOFF  (12u<<20)            // 3 * 128 * 2048 bf16 = 1.5 MiB
#define OPOFF  (14u<<20)            // ks=1..3 partial O, fp32, 3 x 8 MiB
#define LPOFF  (OPOFF + 25165824u)  // l partials [4][16384] fp32

// ---------------------------------------------------------------------------
// W convert+transpose: W[2048][128] fp32 -> Wt[mat][128][2048] bf16.
// Wq pre-scaled by log2(e)/sqrt(H) so attention uses bare exp2.
// ---------------------------------------------------------------------------
__global__ __launch_bounds__(256) void cvtw_kernel(
    const float* __restrict__ Wq, const float* __restrict__ Wk,
    const float* __restrict__ Wv, bf16* __restrict__ Wtb)
{
    __shared__ __align__(16) bf16 U[128 * 72];   // [n][k], stride 72
    const int tid = threadIdx.x;
    const int m  = blockIdx.x >> 5;              // 0..2
    const int kt = blockIdx.x & 31;              // 0..31
    const int k0 = kt * 64;
    const float* W = (m == 0) ? Wq : ((m == 1) ? Wk : Wv);
    const float sc = (m == 0) ? 0.12753102105128444f : 1.0f;  // log2e/sqrt(128)

    #pragma unroll
    for (int u = 0; u < 8; u++) {
        int id = tid + u * 256;
        int kr = id >> 5, c4 = id & 31;
        float4 v = *(const float4*)(W + (size_t)(k0 + kr) * H_ + c4 * 4);
        U[(c4*4 + 0) * 72 + kr] = (bf16)(v.x * sc);
        U[(c4*4 + 1) * 72 + kr] = (bf16)(v.y * sc);
        U[(c4*4 + 2) * 72 + kr] = (bf16)(v.z * sc);
        U[(c4*4 + 3) * 72 + kr] = (bf16)(v.w * sc);
    }
    __syncthreads();
    #pragma unroll
    for (int u = 0; u < 4; u++) {
        int id = tid + u * 256;
        int n = id >> 3, kc = id & 7;
        bf16x8 v = *(const bf16x8*)((const char*)U + n * 144 + kc * 16);
        *(bf16x8*)((char*)Wtb + (size_t)m * 524288 + (size_t)n * 4096
                   + k0 * 2 + kc * 16) = v;
    }
}

// ---------------------------------------------------------------------------
// Fused QKV projection, 32x32x16 MFMA. Block 512 thr / 8 waves, M-tile 64.
// (unchanged from round 6 — near its HBM/LDS floor)
// ---------------------------------------------------------------------------
__global__ __launch_bounds__(512, 2) void proj_kernel(
    const float* __restrict__ X, const bf16* __restrict__ Wtb,
    bf16* __restrict__ Qb, bf16* __restrict__ Kb, bf16* __restrict__ Vtb)
{
    __shared__ __align__(16) char smem[114688];

    const int tid = threadIdx.x;
    const int w = tid >> 6, lane = tid & 63;
    const int c31 = lane & 31, kh = lane >> 5;
    const int mh = w >> 2;
    const int ng = w & 3;
    const int m0 = blockIdx.x * 64;

    f32x16 acc[3];
    #pragma unroll
    for (int t = 0; t < 3; t++)
        #pragma unroll
        for (int r = 0; r < 16; r++) acc[t][r] = 0.f;

    #pragma unroll
    for (int u = 0; u < 6; u++) {
        int s = tid + u * 512;
        int n = s >> 3, ccs = s & 7;
        int kc = ccs ^ (n & 7);
        int mat = n >> 7, ncol = n & 127;
        cp16(smem + 16384 + s * 16,
             (const char*)Wtb + (size_t)mat * 524288 + (size_t)ncol * 4096 + kc * 16);
    }
    {
        int r = tid >> 3, cc = tid & 7;
        const float* src = X + (size_t)(m0 + r) * D_ + cc * 8;
        float4 v0 = *(const float4*)src;
        float4 v1 = *(const float4*)(src + 4);
        union { bf16 h[8]; uint4 u4; } pk;
        pk.h[0]=(bf16)v0.x; pk.h[1]=(bf16)v0.y; pk.h[2]=(bf16)v0.z; pk.h[3]=(bf16)v0.w;
        pk.h[4]=(bf16)v1.x; pk.h[5]=(bf16)v1.y; pk.h[6]=(bf16)v1.z; pk.h[7]=(bf16)v1.w;
        *(uint4*)(smem + (r * 8 + (cc ^ (r & 7))) * 16) = pk.u4;
    }
    __syncthreads();

    for (int it = 0; it < 32; it++) {
        const int cur = it & 1;
        char* xcur = smem + cur * 8192;
        char* wcur = smem + 16384 + cur * 49152;
        float4 xv0, xv1;
        if (it < 31) {
            const int k1 = (it + 1) * 64;
            char* wnxt = smem + 16384 + (cur ^ 1) * 49152;
            #pragma unroll
            for (int u = 0; u < 6; u++) {
                int s = tid + u * 512;
                int n = s >> 3, ccs = s & 7;
                int kc = ccs ^ (n & 7);
                int mat = n >> 7, ncol = n & 127;
                cp16(wnxt + s * 16,
                     (const char*)Wtb + (size_t)mat * 524288 + (size_t)ncol * 4096
                     + k1 * 2 + kc * 16);
            }
            int r = tid >> 3, cc = tid & 7;
            const float* src = X + (size_t)(m0 + r) * D_ + k1 + cc * 8;
            xv0 = *(const float4*)src;
            xv1 = *(const float4*)(src + 4);
        }
        #pragma unroll
        for (int s = 0; s < 4; s++) {
            int c = s * 2 + kh;
            int rr = mh * 32 + c31;
            bf16x8 af = *(const bf16x8*)(xcur + (rr * 8 + (c ^ (rr & 7))) * 16);
            #pragma unroll
            for (int t = 0; t < 3; t++) {
                int n = ng * 96 + t * 32 + c31;
                bf16x8 bfr = *(const bf16x8*)(wcur + (n * 8 + (c ^ (n & 7))) * 16);
                acc[t] = MFMA32(af, bfr, acc[t]);
            }
        }
        if (it < 31) {
            char* xnxt = smem + (cur ^ 1) * 8192;
            int r = tid >> 3, cc = tid & 7;
            union { bf16 h[8]; uint4 u4; } pk;
            pk.h[0]=(bf16)xv0.x; pk.h[1]=(bf16)xv0.y; pk.h[2]=(bf16)xv0.z; pk.h[3]=(bf16)xv0.w;
            pk.h[4]=(bf16)xv1.x; pk.h[5]=(bf16)xv1.y; pk.h[6]=(bf16)xv1.z; pk.h[7]=(bf16)xv1.w;
            *(uint4*)(xnxt + (r * 8 + (cc ^ (r & 7))) * 16) = pk.u4;
        }
        __syncthreads();
    }

    #pragma unroll
    for (int t = 0; t < 3; t++) {
        int nb = ng * 96 + t * 32;
        if ((nb >> 7) == 2) {
            int ncol = (nb & 127) + c31;
            #pragma unroll
            for (int g = 0; g < 4; g++) {
                int m = m0 + mh * 32 + g * 8 + kh * 4;
                union { bf16 h[4]; uint2 u2; } pk;
                #pragma unroll
                for (int e = 0; e < 4; e++) pk.h[e] = (bf16)acc[t][g*4 + e];
                *(uint2*)((char*)Vtb + (size_t)ncol * 32768 + (size_t)m * 2) = pk.u2;
            }
        }
    }
    bf16* U = (bf16*)smem;
    #pragma unroll
    for (int mat = 0; mat < 2; mat++) {
        __syncthreads();
        #pragma unroll
        for (int t = 0; t < 3; t++) {
            int nb = ng * 96 + t * 32;
            if ((nb >> 7) == mat) {
                int lcol = (nb & 127) + c31;
                #pragma unroll
                for (int r = 0; r < 16; r++) {
                    int row = mh * 32 + (r & 3) + 8 * (r >> 2) + 4 * kh;
                    U[row * 136 + lcol] = (bf16)acc[t][r];
                }
            }
        }
        __syncthreads();
        bf16* og = (mat == 0) ? Qb : Kb;
        #pragma unroll
        for (int u = 0; u < 2; u++) {
            int id = tid + u * 512;
            int rr = id >> 4, cc = id & 15;
            bf16x8 v = *(const bf16x8*)((const char*)U + rr * 272 + cc * 16);
            *(bf16x8*)((char*)og + (size_t)(m0 + rr) * 256 + cc * 16) = v;
        }
    }
}

// ---------------------------------------------------------------------------
// Flash attention v2: Q-tile 128, 4 waves (256 thr), keys 64/iter, ks/4.
// S via MFMA16 computing D[key][m] (A=K, B=Q) -> lane holds 4 consecutive
// keys -> P written as b64 into P[m][key] (pitch 144B), PV via MFMA32.
// Ks double-buffered; Vs single-buffered (prefetch after PV barrier).
// Grid 512 = 32 qt x 16 slices (b,ks); 2 blocks/CU.
// ---------------------------------------------------------------------------
__global__ __launch_bounds__(256, 2) void attn_kernel(
    const bf16* __restrict__ Qb, const bf16* __restrict__ Kb,
    const bf16* __restrict__ Vtb,
    float* __restrict__ Out0, float* __restrict__ Opart,
    float* __restrict__ lpart)
{
    __shared__ __align__(16) char smem[68608];
    // Ks: 0/16384 (2 x 16KB) | Vs: 32768 (16KB) | P: 49152 (128x144B) |
    // lred: 67584 (2*128 f32)

    const int tid = threadIdx.x;
    const int w = tid >> 6, lane = tid & 63;
    const int c15 = lane & 15, quad = (lane >> 4) & 3;
    const int c31 = lane & 31, kh = lane >> 5;

    const int bx = blockIdx.x;
    const int slice = bx & 15;          // b*4 + ks  (XCD-friendly)
    const int qt = bx >> 4;             // 0..31
    const int b = slice >> 2, ks = slice & 3;
    const int row0 = b*T_ + qt*128;
    const int kvrow = b*T_ + ks*1024;

    const int kg = w & 1;               // key half (32) for S
    const int ms = w >> 1;              // m half (64 rows)
    const int nh = w & 1;               // n half (64 cols) for PV

    // Q B-frags for MFMA16: B[m = c15][k = quad*8+j]; 4 m-groups x 4 k-frags
    bf16x8 qf[4][4];
    #pragma unroll
    for (int mg = 0; mg < 4; mg++) {
        const char* qrow = (const char*)Qb
            + (size_t)(row0 + ms*64 + mg*16 + c15) * 256 + quad*16;
        #pragma unroll
        for (int kk = 0; kk < 4; kk++)
            qf[mg][kk] = *(const bf16x8*)(qrow + kk*64);
    }

    f32x16 o[2][2];
    #pragma unroll
    for (int g = 0; g < 2; g++)
        #pragma unroll
        for (int nn = 0; nn < 2; nn++)
            #pragma unroll
            for (int r = 0; r < 16; r++) o[g][nn][r] = 0.f;
    float lsum[4] = {0.f, 0.f, 0.f, 0.f};

    // prologue: K(0) -> Ks[0], V(0) -> Vs
    #pragma unroll
    for (int u = 0; u < 4; u++) {
        int s = tid + u*256;
        int r = s >> 4, csw = s & 15;
        int cg = (csw & 8) | ((csw ^ r) & 7);
        cp16(smem + s*16, (const char*)Kb + (size_t)(kvrow + r)*256 + cg*16);
    }
    #pragma unroll
    for (int u = 0; u < 4; u++) {
        int s = tid + u*256;
        int h = s >> 3, ccsw = s & 7;
        int cc = (ccsw ^ h) & 7;
        cp16(smem + 32768 + s*16,
             (const char*)Vtb + (size_t)h*32768 + (size_t)kvrow*2 + cc*16);
    }
    __syncthreads();

    for (int it = 0; it < 16; it++) {
        const int cur = it & 1;
        char* ksb = smem + cur*16384;
        if (it < 15) {
            const int knx = kvrow + (it + 1)*64;
            char* kn = smem + (cur ^ 1)*16384;
            #pragma unroll
            for (int u = 0; u < 4; u++) {
                int s = tid + u*256;
                int r = s >> 4, csw = s & 15;
                int cg = (csw & 8) | ((csw ^ r) & 7);
                cp16(kn + s*16, (const char*)Kb + (size_t)(knx + r)*256 + cg*16);
            }
        }

        // S: D[key][m] via MFMA16(A=K, B=Q). Wave: 64m x 32keys.
        bf16* Pp = (bf16*)(smem + 49152);
        #pragma unroll
        for (int kg16 = 0; kg16 < 2; kg16++) {
            const int key = kg*32 + kg16*16 + c15;
            bf16x8 kf[4];
            #pragma unroll
            for (int kk = 0; kk < 4; kk++) {
                int ck = kk*4 + quad;
                kf[kk] = *(const bf16x8*)(ksb
                           + (key*16 + ((ck & 8) | ((ck ^ key) & 7)))*16);
            }
            #pragma unroll
            for (int mg = 0; mg < 4; mg++) {
                f32x4 sc = (f32x4){0.f,0.f,0.f,0.f};
                #pragma unroll
                for (int kk = 0; kk < 4; kk++)
                    sc = MFMA16(kf[kk], qf[mg][kk], sc);
                // lane holds keys kg*32+kg16*16+quad*4+{0..3} for m-col c15
                int m = ms*64 + mg*16 + c15;
                int k0 = kg*32 + kg16*16 + quad*4;
                union { bf16 h[4]; uint2 u2; } pk;
                #pragma unroll
                for (int r = 0; r < 4; r++) {
                    float p = exp2f(sc[r]);
                    lsum[mg] += p;
                    pk.h[r] = (bf16)p;
                }
                *(uint2*)((char*)Pp + m*144 + k0*2) = pk.u2;
            }
        }
        __syncthreads();   // drains K/V prefetch; P visible

        // PV: O += P V, MFMA32. Wave: 64m x 64n.
        char* vsb = smem + 32768;
        #pragma unroll
        for (int s2 = 0; s2 < 4; s2++) {
            int cv = s2*2 + kh;
            bf16x8 pf[2], vfr[2];
            #pragma unroll
            for (int g = 0; g < 2; g++)
                pf[g] = *(const bf16x8*)(smem + 49152
                           + (ms*64 + g*32 + c31)*144 + s2*32 + kh*16);
            #pragma unroll
            for (int nn = 0; nn < 2; nn++) {
                int n = nh*64 + nn*32 + c31;
                vfr[nn] = *(const bf16x8*)(vsb + (n*8 + ((cv ^ n) & 7))*16);
            }
            #pragma unroll
            for (int g = 0; g < 2; g++)
                #pragma unroll
                for (int nn = 0; nn < 2; nn++)
                    o[g][nn] = MFMA32(pf[g], vfr[nn], o[g][nn]);
        }
        __syncthreads();   // PV reads done -> Vs / P safe to overwrite

        if (it < 15) {
            const int knx = kvrow + (it + 1)*64;
            #pragma unroll
            for (int u = 0; u < 4; u++) {
                int s = tid + u*256;
                int h = s >> 3, ccsw = s & 7;
                int cc = (ccsw ^ h) & 7;
                cp16(smem + 32768 + s*16,
                     (const char*)Vtb + (size_t)h*32768 + (size_t)knx*2 + cc*16);
            }
        }
    }

    // lsum: reduce over quads (lanes sharing c15), publish per-row l
    float* lred = (float*)(smem + 67584);
    #pragma unroll
    for (int mg = 0; mg < 4; mg++) {
        float v = lsum[mg];
        v += __shfl_xor(v, 16);
        v += __shfl_xor(v, 32);
        if (lane < 16)
            lred[kg*128 + ms*64 + mg*16 + c15] = v;
    }
    __syncthreads();
    if (tid < 128)
        lpart[ks*M_ + row0 + tid] = lred[tid] + lred[128 + tid];

    float* Od = (ks == 0) ? Out0 : (Opart + (size_t)(ks - 1) * M_ * H_);
    #pragma unroll
    for (int g = 0; g < 2; g++)
        #pragma unroll
        for (int nn = 0; nn < 2; nn++)
            #pragma unroll
            for (int r = 0; r < 16; r++) {
                int m = ms*64 + g*32 + (r & 3) + 8*(r >> 2) + 4*kh;
                int n = nh*64 + nn*32 + c31;
                Od[(size_t)(row0 + m)*H_ + n] = o[g][nn][r];
            }
}

// ---------------------------------------------------------------------------
// Merge: out = (O0 + O1 + O2 + O3) / (l0 + l1 + l2 + l3)
// ---------------------------------------------------------------------------
__global__ __launch_bounds__(256) void merge_kernel(
    float* __restrict__ Out, const float* __restrict__ Opart,
    const float* __restrict__ lp)
{
    int id = blockIdx.x * 256 + threadIdx.x;   // 524288 float4 groups
    int row = id >> 5;
    float inv = 1.0f / (lp[row] + lp[M_ + row] + lp[2*M_ + row] + lp[3*M_ + row]);
    float4 a = *(const float4*)(Out + (size_t)id*4);
    float4 b1 = *(const float4*)(Opart + (size_t)id*4);
    float4 b2 = *(const float4*)(Opart + (size_t)M_*H_ + (size_t)id*4);
    float4 b3 = *(const float4*)(Opart + (size_t)2*M_*H_ + (size_t)id*4);
    float4 rr;
    rr.x = (a.x + b1.x + b2.x + b3.x) * inv;
    rr.y = (a.y + b1.y + b2.y + b3.y) * inv;
    rr.z = (a.z + b1.z + b2.z + b3.z) * inv;
    rr.w = (a.w + b1.w + b2.w + b3.w) * inv;
    *(float4*)(Out + (size_t)id*4) = rr;
}

extern "C" void kernel_launch(void* const* d_in, const int* in_sizes, int n_in,
                              void* d_out, int out_size, void* d_ws, size_t ws_size,
                              hipStream_t stream) {
    const float* x  = (const float*)d_in[0];
    const float* Wq = (const float*)d_in[1];
    const float* Wk = (const float*)d_in[2];
    const float* Wv = (const float*)d_in[3];
    float* outp = (float*)d_out;
    char* ws = (char*)d_ws;

    bf16* Qb  = (bf16*)(ws + QOFF);
    bf16* Kb  = (bf16*)(ws + KOFF);
    bf16* Vtb = (bf16*)(ws + VTOFF);
    bf16* Wtb = (bf16*)(ws + WTOFF);
    float* Op  = (float*)(ws + OPOFF);
    float* lp  = (float*)(ws + LPOFF);

    cvtw_kernel<<<96, 256, 0, stream>>>(Wq, Wk, Wv, Wtb);
    proj_kernel<<<M_/64, 512, 0, stream>>>(x, Wtb, Qb, Kb, Vtb);
    attn_kernel<<<512, 256, 0, stream>>>(Qb, Kb, Vtb, outp, Op, lp);
    merge_kernel<<<2048, 256, 0, stream>>>(outp, Op, lp);
}